// Round 6
// baseline (206.133 us; speedup 1.0000x reference)
//
#include <hip/hip_runtime.h>

// ConfidenceProtoSegHead v4: sim = x(131072x256) . protosT(256x190), max over 10,
// LayerNorm over 19, write [b,19,h,w].
// Split bf16: x=xh+xl, p=ph+pl; sim ~= xh.ph + xl.ph + xh.pl (fp32 MFMA accum).
//
// v4 vs v3 (pipeline only; geometry/layout/numerics identical):
//  - depth-2 A register prefetch (two f32x2[4] buffers, constant-folded selection)
//  - counted publish barrier: s_waitcnt vmcnt(7) lgkmcnt(0); s_barrier
//    (retires the 3 B-glls, keeps the 4 depth-2 A loads in flight; vmcnt(0) at tail)
//  - sched_barrier(0) fences pin VMEM issue order so the counts stay valid
//  - B gll issued immediately after the mid barrier into the just-read buffer

#define CC_   256
#define HW_   32768
#define NPIX_ 131072
#define NCLS_ 19
#define MBLK_ 128
#define SIMST_ 194            // padded f32 stride for epilogue sims tile

typedef __attribute__((ext_vector_type(8)))  short bf16x8;
typedef __attribute__((ext_vector_type(16))) float f32x16;
typedef __attribute__((ext_vector_type(2)))  float f32x2;
typedef __attribute__((ext_vector_type(4)))  unsigned int u32x4;
typedef __attribute__((ext_vector_type(2)))  unsigned int u32x2;

__device__ __forceinline__ void gll16(const void* g, void* l) {
  __builtin_amdgcn_global_load_lds((__attribute__((address_space(1))) void*)(g),
                                   (__attribute__((address_space(3))) void*)(l), 16, 0, 0);
}

#define SCHED() __builtin_amdgcn_sched_barrier(0)
// mid barrier: LDS reads done block-wide; all VMEM stays in flight
#define BAR_LG() do {                                            \
  SCHED();                                                       \
  asm volatile("s_waitcnt lgkmcnt(0)" ::: "memory");             \
  __builtin_amdgcn_s_barrier();                                  \
  SCHED();                                                       \
} while (0)
// publish barrier: retire oldest VMEM down to N (counted), drain LDS, barrier
#define BAR_VMLG(N) do {                                         \
  SCHED();                                                       \
  asm volatile("s_waitcnt vmcnt(" #N ") lgkmcnt(0)" ::: "memory"); \
  __builtin_amdgcn_s_barrier();                                  \
  SCHED();                                                       \
} while (0)

// ---------------- K1: normalize + pack prototypes (32x32 B-frag order) -----
// Bp layout (16B units): (((cc*2+ks)*6 + nt)*2 + part)*64 + koct*32 + cL
__global__ void prep_protos(const float* __restrict__ protos, char* __restrict__ Bp) {
  const int p = blockIdx.x;     // proto column 0..191 (190,191 = zero pad)
  const int l = threadIdx.x;    // 0..63
  __shared__ float pn[256];
  float v[4] = {0.f, 0.f, 0.f, 0.f};
  float sq = 0.f;
  if (p < 190) {
    #pragma unroll
    for (int i = 0; i < 4; ++i) {
      v[i] = protos[p * 256 + l * 4 + i];
      sq += v[i] * v[i];
    }
  }
  #pragma unroll
  for (int off = 32; off > 0; off >>= 1) sq += __shfl_xor(sq, off, 64);
  const float scale = (p < 190) ? 1.0f / (sqrtf(sq) + 1e-12f) : 0.0f;
  #pragma unroll
  for (int i = 0; i < 4; ++i) pn[l * 4 + i] = v[i] * scale;
  __syncthreads();

  const int oct  = l >> 1;      // c-octet 0..31
  const int part = l & 1;       // 0=hi 1=lo
  unsigned int w[4];
  #pragma unroll
  for (int pr = 0; pr < 4; ++pr) {
    const float f0 = pn[oct * 8 + 2 * pr];
    const float f1 = pn[oct * 8 + 2 * pr + 1];
    const unsigned int u0 = __builtin_bit_cast(unsigned int, f0);
    const unsigned int u1 = __builtin_bit_cast(unsigned int, f1);
    if (part == 0) {
      w[pr] = (u1 & 0xFFFF0000u) | (u0 >> 16);
    } else {
      const float t0 = __builtin_bit_cast(float, u0 & 0xFFFF0000u);
      const float t1 = __builtin_bit_cast(float, u1 & 0xFFFF0000u);
      const unsigned int v0 = __builtin_bit_cast(unsigned int, f0 - t0);
      const unsigned int v1 = __builtin_bit_cast(unsigned int, f1 - t1);
      w[pr] = (v1 & 0xFFFF0000u) | (v0 >> 16);
    }
  }
  const int cc = oct >> 2, ks = (oct >> 1) & 1, ko = oct & 1;
  const int nt = p >> 5, cL = p & 31;
  const size_t a16 = (size_t)((((cc * 2 + ks) * 6 + nt) * 2 + part) * 64 + ko * 32 + cL);
  *(u32x4*)(Bp + a16 * 16) = (u32x4){w[0], w[1], w[2], w[3]};
}

// ---------------- K2: fused GEMM + max + LayerNorm -------------------------
// A LDS (16KB): ((ks*2+part)*4 + mt)*64 + koct*32 + row ; row=((pix&1)<<4)|(pix>>1)
// B LDS (2 x 24KB): flat copy of Bp chunk
__device__ __forceinline__ void stageA(char* Albase, const f32x2 (&aLd)[4],
                                       int ksw, int kow, int sub, int mtw, int r15w) {
  #pragma unroll
  for (int e = 0; e < 2; ++e) {
    unsigned int wh[2], wl[2];
    #pragma unroll
    for (int q = 0; q < 2; ++q) {
      const float f0 = aLd[2 * q][e];
      const float f1 = aLd[2 * q + 1][e];
      const unsigned int u0 = __builtin_bit_cast(unsigned int, f0);
      const unsigned int u1 = __builtin_bit_cast(unsigned int, f1);
      wh[q] = (u1 & 0xFFFF0000u) | (u0 >> 16);
      const float t0 = __builtin_bit_cast(float, u0 & 0xFFFF0000u);
      const float t1 = __builtin_bit_cast(float, u1 & 0xFFFF0000u);
      const unsigned int v0 = __builtin_bit_cast(unsigned int, f0 - t0);
      const unsigned int v1 = __builtin_bit_cast(unsigned int, f1 - t1);
      wl[q] = (v1 & 0xFFFF0000u) | (v0 >> 16);
    }
    const int slotH = ((ksw * 2 + 0) * 4 + mtw) * 64 + kow * 32 + e * 16 + r15w;
    const int slotL = ((ksw * 2 + 1) * 4 + mtw) * 64 + kow * 32 + e * 16 + r15w;
    *(u32x2*)(Albase + slotH * 16 + sub * 8) = (u32x2){wh[0], wh[1]};
    *(u32x2*)(Albase + slotL * 16 + sub * 8) = (u32x2){wl[0], wl[1]};
  }
}

__launch_bounds__(512, 4)
__global__ void gemm_kernel(const float* __restrict__ x, const char* __restrict__ Bp,
                            const float* __restrict__ mw, const float* __restrict__ mb,
                            float* __restrict__ out) {
  __shared__ __align__(16) char smem[65536];
  char* Albase = smem;            // 16 KB
  char* Blbase = smem + 16384;    // 2 x 24 KB

  const int tid  = threadIdx.x;
  const int wave = tid >> 6;
  const int lane = tid & 63;
  const int n0   = blockIdx.x * MBLK_;
  const int b    = n0 >> 15;
  const int hw0  = n0 & (HW_ - 1);
  const float* xb = x + (size_t)b * CC_ * HW_ + hw0;

  const int ksw = wave >> 2, kow = (wave >> 1) & 1, sub = wave & 1;
  const int mtw = lane >> 4, r15w = lane & 15;
  const float* xA = xb + (size_t)(wave * 4) * HW_ + 2 * lane;

  const int rowg = wave >> 1, colg = wave & 1;

  f32x16 acc[3];
  #pragma unroll
  for (int nt = 0; nt < 3; ++nt) acc[nt] = (f32x16)(0.0f);

  f32x2 aA[4], aB[4];

  // ---- prologue (VMEM issue order pinned: gllB0 < A0 < A1 < gllB1)
  #pragma unroll
  for (int i = 0; i < 3; ++i)
    gll16(Bp + (size_t)(tid + 512 * i) * 16, Blbase + (tid + 512 * i) * 16);
  SCHED();
  #pragma unroll
  for (int j = 0; j < 4; ++j) aA[j] = *(const f32x2*)(xA + (size_t)j * HW_);
  SCHED();
  #pragma unroll
  for (int j = 0; j < 4; ++j) aB[j] = *(const f32x2*)(xA + (size_t)(32 + j) * HW_);
  SCHED();
  stageA(Albase, aA, ksw, kow, sub, mtw, r15w);   // waits A0 (retires gllB0 too)
  #pragma unroll
  for (int i = 0; i < 3; ++i)
    gll16(Bp + (size_t)(1536 + tid + 512 * i) * 16, Blbase + 24576 + (tid + 512 * i) * 16);
  BAR_LG();
  // invariant: Alds=A0, BL[0]=B0 drained, aB=A1 in flight, gllB1 in flight

  #pragma unroll
  for (int cc = 0; cc < 8; ++cc) {
    const int buf = cc & 1;
    // step1: issue A(cc+2) into the buffer staged last iteration
    if (cc + 2 < 8) {
      f32x2 (&dst)[4] = (cc & 1) ? aB : aA;
      const float* xn = xA + (size_t)((cc + 2) * 32) * HW_;
      #pragma unroll
      for (int j = 0; j < 4; ++j) dst[j] = *(const f32x2*)(xn + (size_t)j * HW_);
    }
    // step2: MFMA phase on current LDS
    const char* Bq = Blbase + buf * 24576;
    #pragma unroll
    for (int ks = 0; ks < 2; ++ks) {
      const bf16x8 ah = *(const bf16x8*)(Albase + (size_t)((((ks * 2 + 0) * 4 + rowg) * 64 + lane) * 16));
      const bf16x8 al = *(const bf16x8*)(Albase + (size_t)((((ks * 2 + 1) * 4 + rowg) * 64 + lane) * 16));
      #pragma unroll
      for (int nt = 0; nt < 3; ++nt) {
        const int ntg = colg * 3 + nt;
        const bf16x8 bh = *(const bf16x8*)(Bq + (size_t)(((ks * 12 + ntg * 2 + 0) * 64 + lane) * 16));
        const bf16x8 bl = *(const bf16x8*)(Bq + (size_t)(((ks * 12 + ntg * 2 + 1) * 64 + lane) * 16));
        acc[nt] = __builtin_amdgcn_mfma_f32_32x32x16_bf16(ah, bh, acc[nt], 0, 0, 0);
        acc[nt] = __builtin_amdgcn_mfma_f32_32x32x16_bf16(al, bh, acc[nt], 0, 0, 0);
        acc[nt] = __builtin_amdgcn_mfma_f32_32x32x16_bf16(ah, bl, acc[nt], 0, 0, 0);
      }
    }
    // step3: mid barrier (LDS reads done; VMEM untouched)
    BAR_LG();
    // step3b: refill the just-read B buffer for chunk cc+2
    if (cc + 2 < 8) {
      #pragma unroll
      for (int i = 0; i < 3; ++i)
        gll16(Bp + (size_t)((cc + 2) * 1536 + tid + 512 * i) * 16,
              Blbase + buf * 24576 + (tid + 512 * i) * 16);
    }
    // step4: stage A(cc+1) (compiler-inserted vmcnt retires those 4 loads)
    if (cc < 7) {
      f32x2 (&stg)[4] = (cc & 1) ? aA : aB;
      stageA(Albase, stg, ksw, kow, sub, mtw, r15w);
      // step5: publish. steady: retire gll(cc+1) [3 oldest], keep A(cc+2)+gll(cc+2)
      if (cc < 6) BAR_VMLG(7);
      else        BAR_VMLG(0);    // tail: nothing left to keep in flight
    }
  }

  // ---- epilogue: 2 rounds of 64 pixels through LDS (all VMEM/LDS quiesced)
  float* sims = (float*)smem;       // [64][SIMST_] = 48.5 KB
  #pragma unroll 1
  for (int r = 0; r < 2; ++r) {
    if ((rowg >> 1) == r) {
      const int srow = (rowg & 1) * 32;
      #pragma unroll
      for (int nt = 0; nt < 3; ++nt) {
        #pragma unroll
        for (int q = 0; q < 16; ++q) {
          const int row = (q & 3) + 8 * (q >> 2) + 4 * (lane >> 5);
          sims[(srow + row) * SIMST_ + (colg * 3 + nt) * 32 + (lane & 31)] = acc[nt][q];
        }
      }
    }
    __syncthreads();
    if (tid < 64) {
      float mx[NCLS_];
      #pragma unroll
      for (int k = 0; k < NCLS_; ++k) {
        const float* rp = sims + tid * SIMST_ + k * 10;
        const f32x2 v0 = *(const f32x2*)(rp + 0);
        const f32x2 v1 = *(const f32x2*)(rp + 2);
        const f32x2 v2 = *(const f32x2*)(rp + 4);
        const f32x2 v3 = *(const f32x2*)(rp + 6);
        const f32x2 v4 = *(const f32x2*)(rp + 8);
        float m01 = fmaxf(fmaxf(v0[0], v0[1]), fmaxf(v1[0], v1[1]));
        float m23 = fmaxf(fmaxf(v2[0], v2[1]), fmaxf(v3[0], v3[1]));
        mx[k] = fmaxf(fmaxf(m01, m23), fmaxf(v4[0], v4[1]));
      }
      float mu = 0.f;
      #pragma unroll
      for (int k = 0; k < NCLS_; ++k) mu += mx[k];
      mu *= (1.0f / NCLS_);
      float var = 0.f;
      #pragma unroll
      for (int k = 0; k < NCLS_; ++k) { const float d = mx[k] - mu; var += d * d; }
      var *= (1.0f / NCLS_);
      const float rstd = rsqrtf(var + 1e-5f);
      const int s = tid & 31;
      const int hw = hw0 + (2 * r + (tid >> 5)) * 32 + ((s & 15) << 1) + (s >> 4);
      #pragma unroll
      for (int k = 0; k < NCLS_; ++k) {
        out[((size_t)(b * NCLS_ + k) << 15) + hw] = (mx[k] - mu) * rstd * mw[k] + mb[k];
      }
    }
    __syncthreads();
  }
}

extern "C" void kernel_launch(void* const* d_in, const int* in_sizes, int n_in,
                              void* d_out, int out_size, void* d_ws, size_t ws_size,
                              hipStream_t stream) {
  const float* x      = (const float*)d_in[0];
  const float* protos = (const float*)d_in[1];
  const float* mw     = (const float*)d_in[2];
  const float* mb     = (const float*)d_in[3];
  float* out = (float*)d_out;
  char* Bp   = (char*)d_ws;       // 192 KB packed prototypes

  prep_protos<<<192, 64, 0, stream>>>(protos, Bp);
  gemm_kernel<<<NPIX_ / MBLK_, 512, 0, stream>>>(x, Bp, mw, mb, out);
}